// Round 1
// baseline (161.461 us; speedup 1.0000x reference)
//
#include <hip/hip_runtime.h>

#define Bn 8
#define Sn 8192
#define Dn 128
#define MEMn 128
#define STn 64
#define NCn 128

typedef _Float16 f16;
typedef f16 f16x4 __attribute__((ext_vector_type(4)));
typedef float f32x4 __attribute__((ext_vector_type(4)));

static __device__ __forceinline__ f32x4 mfma16(f16x4 a, f16x4 b, f32x4 c) {
  return __builtin_amdgcn_mfma_f32_16x16x16f16(a, b, c, 0, 0, 0);
}

// ---------------- weight conversion ----------------
__global__ __launch_bounds__(256) void k_prep(
    const float* __restrict__ Wq, const float* __restrict__ Wk,
    const float* __restrict__ Wv, const float* __restrict__ Wout,
    f16* __restrict__ wq, f16* __restrict__ wk,
    f16* __restrict__ wv, f16* __restrict__ wout) {
  int i = blockIdx.x * 256 + threadIdx.x;  // 0..16383
  wq[i] = (f16)Wq[i];
  wk[i] = (f16)Wk[i];
  wv[i] = (f16)Wv[i];
  wout[i] = (f16)Wout[i];
}

// ---------------- projections + chunk outer product ----------------
// grid = B*NC (one WG per (b,c)); 256 threads = 4 waves
__global__ __launch_bounds__(256) void k_proj(
    const float* __restrict__ x, const float* __restrict__ gw, const float* __restrict__ gb,
    const f16* __restrict__ wq, const f16* __restrict__ wk, const f16* __restrict__ wv,
    f16* __restrict__ qg, f16* __restrict__ wtg, float* __restrict__ gavg) {
  __shared__ f16 Xs[64][136];   // x chunk, f16, padded rows
  __shared__ f16 kT[128][72];   // (k*g)^T : [d][s]
  __shared__ f16 vT[128][72];   // v^T     : [m][s]
  __shared__ float gs[64];

  const int blk = blockIdx.x;
  const int b = blk >> 7, c = blk & 127;
  const int tid = threadIdx.x;
  const int w = tid >> 6, lane = tid & 63;
  const int r16 = lane & 15, g4 = lane >> 4;

  // ---- phase 1: stage X (f32->f16) + gate ----
  {
    const int s = tid >> 2, quarter = tid & 3;
    const float4* xr = (const float4*)(x + ((size_t)b * Sn + (size_t)c * STn + s) * Dn) + quarter * 8;
    float gpart = 0.f;
#pragma unroll
    for (int i = 0; i < 8; ++i) {
      float4 v4 = xr[i];
      int col = quarter * 32 + i * 4;
      Xs[s][col + 0] = (f16)v4.x;
      Xs[s][col + 1] = (f16)v4.y;
      Xs[s][col + 2] = (f16)v4.z;
      Xs[s][col + 3] = (f16)v4.w;
      gpart += v4.x * gw[col] + v4.y * gw[col + 1] + v4.z * gw[col + 2] + v4.w * gw[col + 3];
    }
    gpart += __shfl_xor(gpart, 1);
    gpart += __shfl_xor(gpart, 2);
    if (quarter == 0) gs[s] = 1.f / (1.f + __expf(-(gpart + gb[0])));
  }
  __syncthreads();
  if (tid == 0) {
    float sum = 0.f;
#pragma unroll
    for (int i = 0; i < 64; ++i) sum += gs[i];
    gavg[blk] = sum * (1.f / 64.f);
  }

  f32x4 acc[8];
  const f32x4 zero4 = {0.f, 0.f, 0.f, 0.f};

  // ---- q = X @ Wq^T ----
#pragma unroll
  for (int t = 0; t < 8; ++t) acc[t] = zero4;
#pragma unroll
  for (int kk = 0; kk < 8; ++kk) {
    f16x4 af = *(const f16x4*)&Xs[w * 16 + r16][kk * 16 + g4 * 4];
#pragma unroll
    for (int t = 0; t < 8; ++t) {
      f16x4 bf = *(const f16x4*)&wq[(size_t)(t * 16 + r16) * Dn + kk * 16 + g4 * 4];
      acc[t] = mfma16(af, bf, acc[t]);
    }
  }
  {
    f16* qdst = qg + ((size_t)blk * STn + w * 16 + g4 * 4) * Dn + r16;
#pragma unroll
    for (int t = 0; t < 8; ++t)
#pragma unroll
      for (int j = 0; j < 4; ++j)
        qdst[(size_t)j * Dn + t * 16] = (f16)acc[t][j];
  }

  // ---- k (gated, transposed into LDS) ----
#pragma unroll
  for (int t = 0; t < 8; ++t) acc[t] = zero4;
#pragma unroll
  for (int kk = 0; kk < 8; ++kk) {
    f16x4 af = *(const f16x4*)&Xs[w * 16 + r16][kk * 16 + g4 * 4];
#pragma unroll
    for (int t = 0; t < 8; ++t) {
      f16x4 bf = *(const f16x4*)&wk[(size_t)(t * 16 + r16) * Dn + kk * 16 + g4 * 4];
      acc[t] = mfma16(af, bf, acc[t]);
    }
  }
#pragma unroll
  for (int t = 0; t < 8; ++t)
#pragma unroll
    for (int j = 0; j < 4; ++j) {
      int s = w * 16 + g4 * 4 + j;
      kT[t * 16 + r16][s] = (f16)(acc[t][j] * gs[s]);
    }

  // ---- v (transposed into LDS) ----
#pragma unroll
  for (int t = 0; t < 8; ++t) acc[t] = zero4;
#pragma unroll
  for (int kk = 0; kk < 8; ++kk) {
    f16x4 af = *(const f16x4*)&Xs[w * 16 + r16][kk * 16 + g4 * 4];
#pragma unroll
    for (int t = 0; t < 8; ++t) {
      f16x4 bf = *(const f16x4*)&wv[(size_t)(t * 16 + r16) * Dn + kk * 16 + g4 * 4];
      acc[t] = mfma16(af, bf, acc[t]);
    }
  }
#pragma unroll
  for (int t = 0; t < 8; ++t)
#pragma unroll
    for (int j = 0; j < 4; ++j) {
      int s = w * 16 + g4 * 4 + j;
      vT[t * 16 + r16][s] = (f16)acc[t][j];
    }
  __syncthreads();

  // ---- WT[m][d] = sum_s v[s][m] * k'(s,d)  (A = vT, B from kT) ----
  f32x4 acc2[2][8];
#pragma unroll
  for (int rt = 0; rt < 2; ++rt)
#pragma unroll
    for (int t = 0; t < 8; ++t) acc2[rt][t] = zero4;
#pragma unroll
  for (int kk = 0; kk < 4; ++kk) {
    f16x4 a0 = *(const f16x4*)&vT[w * 32 + r16][kk * 16 + g4 * 4];
    f16x4 a1 = *(const f16x4*)&vT[w * 32 + 16 + r16][kk * 16 + g4 * 4];
#pragma unroll
    for (int t = 0; t < 8; ++t) {
      f16x4 bf = *(const f16x4*)&kT[t * 16 + r16][kk * 16 + g4 * 4];
      acc2[0][t] = mfma16(a0, bf, acc2[0][t]);
      acc2[1][t] = mfma16(a1, bf, acc2[1][t]);
    }
  }
#pragma unroll
  for (int rt = 0; rt < 2; ++rt) {
    f16* wdst = wtg + ((size_t)blk * MEMn + w * 32 + rt * 16 + g4 * 4) * Dn + r16;
#pragma unroll
    for (int t = 0; t < 8; ++t)
#pragma unroll
      for (int j = 0; j < 4; ++j)
        wdst[(size_t)j * Dn + t * 16] = (f16)acc2[rt][t][j];
  }
}

// ---------------- per-element scalar-decay scan ----------------
// grid = B * (D*MEM/256) = 512; thread owns one (m,d) element of M for one batch
__global__ __launch_bounds__(256) void k_scan(
    const f16* __restrict__ wtg, const float* __restrict__ gavg, f16* __restrict__ mtg) {
  const int blk = blockIdx.x;
  const int b = blk >> 6, eb = blk & 63;
  const int e = eb * 256 + threadIdx.x;  // (m*128 + d)
  const f16* wp = wtg + (size_t)b * NCn * 16384 + e;
  f16* mp = mtg + (size_t)b * NCn * 16384 + e;
  const float* ga = gavg + b * NCn;

  float M = 0.f;
  float wv8[8], av8[8];
#pragma unroll
  for (int i = 0; i < 8; ++i) {
    wv8[i] = (float)wp[(size_t)i * 16384];
    av8[i] = ga[i];
  }
  for (int g = 0; g < 16; ++g) {
    float wn[8], an[8];
    if (g < 15) {
#pragma unroll
      for (int i = 0; i < 8; ++i) {
        wn[i] = (float)wp[(size_t)((g + 1) * 8 + i) * 16384];
        an[i] = ga[(g + 1) * 8 + i];
      }
    }
#pragma unroll
    for (int i = 0; i < 8; ++i) {
      int cc = g * 8 + i;
      mp[(size_t)cc * 16384] = (f16)M;            // exclusive prefix: M_{c-1}
      M = (1.f - av8[i]) * M + wv8[i];
    }
#pragma unroll
    for (int i = 0; i < 8; ++i) { wv8[i] = wn[i]; av8[i] = an[i]; }
  }
}

// ---------------- reads + output projection ----------------
// grid = B*NC; out_c = (q_c @ M_{c-1}) @ Wout^T
__global__ __launch_bounds__(256) void k_out(
    const f16* __restrict__ qg, const f16* __restrict__ mtg, const f16* __restrict__ wout,
    float* __restrict__ outp) {
  __shared__ f16 Qs[64][136];   // q chunk; later reused for R = q@M
  __shared__ f16 Ms[128][136];  // M^T : [m][d]
  const int blk = blockIdx.x;
  const int b = blk >> 7, c = blk & 127;
  const int tid = threadIdx.x;
  const int w = tid >> 6, lane = tid & 63;
  const int r16 = lane & 15, g4 = lane >> 4;

  {
    const uint4* s4 = (const uint4*)(qg + (size_t)blk * STn * Dn);
#pragma unroll
    for (int i = 0; i < 4; ++i) {
      int idx = tid + i * 256;
      uint4 v4 = s4[idx];
      int e = idx * 8;
      *(uint4*)&Qs[e >> 7][e & 127] = v4;
    }
    const uint4* m4 = (const uint4*)(mtg + (size_t)blk * MEMn * Dn);
#pragma unroll
    for (int i = 0; i < 8; ++i) {
      int idx = tid + i * 256;
      uint4 v4 = m4[idx];
      int e = idx * 8;
      *(uint4*)&Ms[e >> 7][e & 127] = v4;
    }
  }
  __syncthreads();

  const f32x4 zero4 = {0.f, 0.f, 0.f, 0.f};
  f32x4 acc[8];
#pragma unroll
  for (int t = 0; t < 8; ++t) acc[t] = zero4;
#pragma unroll
  for (int kk = 0; kk < 8; ++kk) {
    f16x4 af = *(const f16x4*)&Qs[w * 16 + r16][kk * 16 + g4 * 4];
#pragma unroll
    for (int t = 0; t < 8; ++t) {
      f16x4 bf = *(const f16x4*)&Ms[t * 16 + r16][kk * 16 + g4 * 4];
      acc[t] = mfma16(af, bf, acc[t]);
    }
  }
  __syncthreads();  // done reading Qs as q
#pragma unroll
  for (int t = 0; t < 8; ++t)
#pragma unroll
    for (int j = 0; j < 4; ++j)
      Qs[w * 16 + g4 * 4 + j][t * 16 + r16] = (f16)acc[t][j];  // R row-major
  __syncthreads();

  f32x4 a2[8];
#pragma unroll
  for (int t = 0; t < 8; ++t) a2[t] = zero4;
#pragma unroll
  for (int kk = 0; kk < 8; ++kk) {
    f16x4 af = *(const f16x4*)&Qs[w * 16 + r16][kk * 16 + g4 * 4];
#pragma unroll
    for (int t = 0; t < 8; ++t) {
      f16x4 bf = *(const f16x4*)&wout[(size_t)(t * 16 + r16) * MEMn + kk * 16 + g4 * 4];
      a2[t] = mfma16(af, bf, a2[t]);
    }
  }
  float* orow = outp + ((size_t)b * Sn + (size_t)c * STn + w * 16 + g4 * 4) * Dn + r16;
#pragma unroll
  for (int t = 0; t < 8; ++t)
#pragma unroll
    for (int j = 0; j < 4; ++j)
      orow[(size_t)j * Dn + t * 16] = a2[t][j];
}

extern "C" void kernel_launch(void* const* d_in, const int* in_sizes, int n_in,
                              void* d_out, int out_size, void* d_ws, size_t ws_size,
                              hipStream_t stream) {
  const float* x = (const float*)d_in[0];
  const float* Wq = (const float*)d_in[1];
  const float* Wk = (const float*)d_in[2];
  const float* Wv = (const float*)d_in[3];
  const float* gw = (const float*)d_in[4];
  const float* gb = (const float*)d_in[5];
  const float* Wout = (const float*)d_in[6];

  char* ws = (char*)d_ws;
  f16* wq16 = (f16*)(ws + 0);
  f16* wk16 = (f16*)(ws + 32768);
  f16* wv16 = (f16*)(ws + 65536);
  f16* wout16 = (f16*)(ws + 98304);
  float* gavg = (float*)(ws + 131072);
  f16* qg = (f16*)(ws + 135168);                         // 16 MB
  f16* wtg = (f16*)(ws + 135168 + 16777216);             // 32 MB
  f16* mtg = (f16*)(ws + 135168 + 16777216 + 33554432);  // 32 MB

  k_prep<<<dim3(64), dim3(256), 0, stream>>>(Wq, Wk, Wv, Wout, wq16, wk16, wv16, wout16);
  k_proj<<<dim3(Bn * NCn), dim3(256), 0, stream>>>(x, gw, gb, wq16, wk16, wv16, qg, wtg, gavg);
  k_scan<<<dim3(Bn * 64), dim3(256), 0, stream>>>(wtg, gavg, mtg);
  k_out<<<dim3(Bn * NCn), dim3(256), 0, stream>>>(qg, mtg, wout16, (float*)d_out);
}

// Round 3
// 108.140 us; speedup vs baseline: 1.4931x; 1.4931x over previous
//
#include <hip/hip_runtime.h>

#define Bn 8
#define Sn 8192
#define Dn 128
#define NCn 128

typedef _Float16 f16;
typedef f16 f16x4 __attribute__((ext_vector_type(4)));
typedef float f32x4 __attribute__((ext_vector_type(4)));

static __device__ __forceinline__ f32x4 mfma16(f16x4 a, f16x4 b, f32x4 c) {
  return __builtin_amdgcn_mfma_f32_16x16x16f16(a, b, c, 0, 0, 0);
}

// Validated (round 0) fragment conventions for mfma_f32_16x16x16f16:
//   A-frag: lane l, reg j = A[l&15][4*(l>>4)+j]      (row read of row-major A)
//   B-frag: lane l, reg j = B[4*(l>>4)+j][l&15]      (row read of row-major B^T)
//   D-frag: lane l, reg j = D[4*(l>>4)+j][l&15]      (scatter store row-major)

// dst[c*136 + r] = (f16)src[r][c]  (transpose, pitch 136)
static __device__ __forceinline__ void stage_T136(const float* __restrict__ src,
                                                  f16* __restrict__ dst, int tid) {
#pragma unroll
  for (int ii = 0; ii < 4; ++ii) {
    int id = ii * 256 + tid;  // 1024 4x4 blocks
    int r4 = id >> 5, c4 = id & 31;
    float4 row[4];
#pragma unroll
    for (int i = 0; i < 4; ++i)
      row[i] = *(const float4*)(src + (r4 * 4 + i) * 128 + c4 * 4);
#pragma unroll
    for (int j = 0; j < 4; ++j) {
      f16x4 col = {(f16)(((const float*)&row[0])[j]), (f16)(((const float*)&row[1])[j]),
                   (f16)(((const float*)&row[2])[j]), (f16)(((const float*)&row[3])[j])};
      *(f16x4*)&dst[(c4 * 4 + j) * 136 + r4 * 4] = col;
    }
  }
}

// ---- precompute: wg0: aT = (Wq^T Wk)^T = Wk^T Wq ; wg1: r2 = (Wv^T Wout^T)^T = Wout Wv ----
// Both stored row-major f16 [128][128] so k_out B-frags are plain row reads.
__global__ __launch_bounds__(256) void k_prep(
    const float* __restrict__ Wq, const float* __restrict__ Wk,
    const float* __restrict__ Wv, const float* __restrict__ Wout,
    f16* __restrict__ aT, f16* __restrict__ r2) {
  __shared__ __align__(16) f16 L[128 * 136];  // A-operand source (row reads)
  __shared__ __align__(16) f16 R[128 * 136];  // B-operand source = (B_op)^T (row reads)
  const int tid = threadIdx.x;
  if (blockIdx.x == 0) {
    // aT = Wk^T Wq : A_op = Wk^T -> L = Wk^T ; B_op = Wq -> R = Wq^T
    stage_T136(Wk, L, tid);
    stage_T136(Wq, R, tid);
  } else {
    // r2 = Wout Wv : A_op = Wout -> L = Wout (row-major copy) ; B_op = Wv -> R = Wv^T
    int r = tid >> 1, h = tid & 1;
#pragma unroll
    for (int i = 0; i < 16; ++i) {
      float4 v = *(const float4*)(Wout + r * 128 + h * 64 + i * 4);
      f16x4 o = {(f16)v.x, (f16)v.y, (f16)v.z, (f16)v.w};
      *(f16x4*)&L[r * 136 + h * 64 + i * 4] = o;
    }
    stage_T136(Wv, R, tid);
  }
  __syncthreads();
  const int w = tid >> 6, lane = tid & 63, r16 = lane & 15, g4 = lane >> 4;
  f32x4 acc[2][8] = {};
#pragma unroll
  for (int kk = 0; kk < 8; ++kk) {
    f16x4 af0 = *(f16x4*)&L[((2 * w) * 16 + r16) * 136 + kk * 16 + g4 * 4];
    f16x4 af1 = *(f16x4*)&L[((2 * w + 1) * 16 + r16) * 136 + kk * 16 + g4 * 4];
#pragma unroll
    for (int ct = 0; ct < 8; ++ct) {
      f16x4 bf = *(f16x4*)&R[(ct * 16 + r16) * 136 + kk * 16 + g4 * 4];
      acc[0][ct] = mfma16(af0, bf, acc[0][ct]);
      acc[1][ct] = mfma16(af1, bf, acc[1][ct]);
    }
  }
  f16* dst = (blockIdx.x == 0) ? aT : r2;
#pragma unroll
  for (int rr = 0; rr < 2; ++rr)
#pragma unroll
    for (int ct = 0; ct < 8; ++ct)
#pragma unroll
      for (int j = 0; j < 4; ++j)
        dst[((2 * w + rr) * 16 + g4 * 4 + j) * 128 + ct * 16 + r16] = (f16)acc[rr][ct][j];
}

// ---- gate + Y_c = (g*x)^T x, row-major [128][128] per (b,c) ----
__global__ __launch_bounds__(512) void k_phase1(
    const float* __restrict__ x, const float* __restrict__ gw, const float* __restrict__ gb,
    f16* __restrict__ wtg, float* __restrict__ gavg) {
  __shared__ __align__(16) f16 Xs[64][136];
  __shared__ __align__(16) f16 XsT[128][72];
  __shared__ float gs[64];
  const int blk = blockIdx.x, b = blk >> 7, c = blk & 127;
  const int tid = threadIdx.x;
  {
    int s = tid >> 3, sub = tid & 7;
    const float* xrow = x + ((size_t)b * Sn + (size_t)c * 64 + s) * Dn;
    float gpart = 0.f;
#pragma unroll
    for (int i = 0; i < 4; ++i) {
      int col = sub * 4 + i * 32;
      float4 v = *(const float4*)(xrow + col);
      float4 g = *(const float4*)(gw + col);
      gpart += v.x * g.x + v.y * g.y + v.z * g.z + v.w * g.w;
      f16x4 h = {(f16)v.x, (f16)v.y, (f16)v.z, (f16)v.w};
      *(f16x4*)&Xs[s][col] = h;
    }
    gpart += __shfl_xor(gpart, 1);
    gpart += __shfl_xor(gpart, 2);
    gpart += __shfl_xor(gpart, 4);
    if (sub == 0) gs[s] = 1.f / (1.f + __expf(-(gpart + gb[0])));
  }
  __syncthreads();
  if (tid == 0) {
    float sum = 0.f;
#pragma unroll
    for (int i = 0; i < 64; ++i) sum += gs[i];
    gavg[blk] = sum * (1.f / 64.f);
  }
  {  // 4x4 register transpose Xs -> XsT
    int s4 = tid & 15, d4 = tid >> 4;
    f16x4 r0 = *(f16x4*)&Xs[s4 * 4 + 0][d4 * 4];
    f16x4 r1 = *(f16x4*)&Xs[s4 * 4 + 1][d4 * 4];
    f16x4 r2v = *(f16x4*)&Xs[s4 * 4 + 2][d4 * 4];
    f16x4 r3 = *(f16x4*)&Xs[s4 * 4 + 3][d4 * 4];
#pragma unroll
    for (int j = 0; j < 4; ++j) {
      f16x4 cv = {r0[j], r1[j], r2v[j], r3[j]};
      *(f16x4*)&XsT[d4 * 4 + j][s4 * 4] = cv;
    }
  }
  __syncthreads();
  const int w = tid >> 6, lane = tid & 63, r16 = lane & 15, g4 = lane >> 4;
  f32x4 acc[8] = {};
#pragma unroll
  for (int kk = 0; kk < 4; ++kk) {
    float4 gv = *(const float4*)&gs[kk * 16 + g4 * 4];
    f16x4 fr = *(f16x4*)&XsT[w * 16 + r16][kk * 16 + g4 * 4];
    f16x4 af = {(f16)((float)fr[0] * gv.x), (f16)((float)fr[1] * gv.y),
                (f16)((float)fr[2] * gv.z), (f16)((float)fr[3] * gv.w)};
#pragma unroll
    for (int ct = 0; ct < 8; ++ct) {
      f16x4 bf = *(f16x4*)&XsT[ct * 16 + r16][kk * 16 + g4 * 4];
      acc[ct] = mfma16(af, bf, acc[ct]);
    }
  }
  f16* wY = wtg + (size_t)blk * 16384;
#pragma unroll
  for (int ct = 0; ct < 8; ++ct)
#pragma unroll
    for (int j = 0; j < 4; ++j)
      wY[(w * 16 + g4 * 4 + j) * 128 + ct * 16 + r16] = (f16)acc[ct][j];
}

// ---- per-element scalar-decay scan (exclusive prefix), validated round 0 ----
__global__ __launch_bounds__(256) void k_scan(
    const f16* __restrict__ wtg, const float* __restrict__ gavg, f16* __restrict__ mtg) {
  const int blk = blockIdx.x;
  const int b = blk >> 6, eb = blk & 63;
  const int e = eb * 256 + threadIdx.x;
  const f16* wp = wtg + (size_t)b * NCn * 16384 + e;
  f16* mp = mtg + (size_t)b * NCn * 16384 + e;
  const float* ga = gavg + b * NCn;

  float M = 0.f;
  float wv8[8], av8[8];
#pragma unroll
  for (int i = 0; i < 8; ++i) {
    wv8[i] = (float)wp[(size_t)i * 16384];
    av8[i] = ga[i];
  }
  for (int g = 0; g < 16; ++g) {
    float wn[8], an[8];
    if (g < 15) {
#pragma unroll
      for (int i = 0; i < 8; ++i) {
        wn[i] = (float)wp[(size_t)((g + 1) * 8 + i) * 16384];
        an[i] = ga[(g + 1) * 8 + i];
      }
    }
#pragma unroll
    for (int i = 0; i < 8; ++i) {
      int cc = g * 8 + i;
      mp[(size_t)cc * 16384] = (f16)M;
      M = (1.f - av8[i]) * M + wv8[i];
    }
#pragma unroll
    for (int i = 0; i < 8; ++i) { wv8[i] = wn[i]; av8[i] = an[i]; }
  }
}

// ---- out_c = ((x_c A) Yhat_{c-1}) B : 3 chained 64x128x128 GEMMs ----
__global__ __launch_bounds__(512) void k_out(
    const float* __restrict__ x, const f16* __restrict__ aT, const f16* __restrict__ r2,
    const f16* __restrict__ mtg, float* __restrict__ outp) {
  __shared__ __align__(16) char raw[17408 * 2 + 34816];
  f16(*Xs)[136] = (f16(*)[136])raw;              // x chunk; aliased by t2 after GEMM2
  f16(*t1L)[136] = (f16(*)[136])(raw + 17408);   // t1 = x A
  f16(*Ms)[136] = (f16(*)[136])(raw + 34816);    // Yhat (symmetric), row-major
  const int blk = blockIdx.x, b = blk >> 7, c = blk & 127;
  const int tid = threadIdx.x;
  {
    int s = tid >> 3, sub = tid & 7;
    const float* xrow = x + ((size_t)b * Sn + (size_t)c * 64 + s) * Dn;
#pragma unroll
    for (int i = 0; i < 4; ++i) {
      int col = sub * 4 + i * 32;
      float4 v = *(const float4*)(xrow + col);
      f16x4 h = {(f16)v.x, (f16)v.y, (f16)v.z, (f16)v.w};
      *(f16x4*)&Xs[s][col] = h;
    }
    const uint4* m4 = (const uint4*)(mtg + (size_t)blk * 16384);
#pragma unroll
    for (int i = 0; i < 4; ++i) {
      int idx = tid + i * 512;         // 2048 uint4 = 128x128 f16
      uint4 v4 = m4[idx];
      int e = idx * 8;
      *(uint4*)&Ms[e >> 7][e & 127] = v4;
    }
  }
  __syncthreads();
  const int w = tid >> 6, lane = tid & 63, r16 = lane & 15, g4 = lane >> 4;
  const int mr = w & 3;            // row-tile of the 64-row chunk
  const int cb = (w >> 2) * 4;     // column-tile base (4 tiles per wave)

  // GEMM1: t1 = x A   (B-frags = row reads of aT = A^T, L2-resident)
  f32x4 acc[4] = {};
#pragma unroll
  for (int kk = 0; kk < 8; ++kk) {
    f16x4 af = *(f16x4*)&Xs[mr * 16 + r16][kk * 16 + g4 * 4];
#pragma unroll
    for (int t = 0; t < 4; ++t) {
      f16x4 bf = *(const f16x4*)&aT[((cb + t) * 16 + r16) * 128 + kk * 16 + g4 * 4];
      acc[t] = mfma16(af, bf, acc[t]);
    }
  }
#pragma unroll
  for (int t = 0; t < 4; ++t) {
#pragma unroll
    for (int j = 0; j < 4; ++j)
      t1L[mr * 16 + g4 * 4 + j][(cb + t) * 16 + r16] = (f16)acc[t][j];
    acc[t] = (f32x4){0.f, 0.f, 0.f, 0.f};
  }
  __syncthreads();  // t1L ready; all Xs reads complete

  // GEMM2: t2 = t1 Yhat  (Yhat symmetric: B-frag = row read of Ms)
#pragma unroll
  for (int kk = 0; kk < 8; ++kk) {
    f16x4 af = *(f16x4*)&t1L[mr * 16 + r16][kk * 16 + g4 * 4];
#pragma unroll
    for (int t = 0; t < 4; ++t) {
      f16x4 bf = *(f16x4*)&Ms[(cb + t) * 16 + r16][kk * 16 + g4 * 4];
      acc[t] = mfma16(af, bf, acc[t]);
    }
  }
#pragma unroll
  for (int t = 0; t < 4; ++t)
#pragma unroll
    for (int j = 0; j < 4; ++j)
      Xs[mr * 16 + g4 * 4 + j][(cb + t) * 16 + r16] = (f16)acc[t][j];  // t2 -> Xs region
  __syncthreads();  // t2 ready

  // GEMM3: out = t2 B2   (B-frags = row reads of r2 = B2^T, L2-resident)
  f32x4 acc3[4] = {};
#pragma unroll
  for (int kk = 0; kk < 8; ++kk) {
    f16x4 af = *(f16x4*)&Xs[mr * 16 + r16][kk * 16 + g4 * 4];
#pragma unroll
    for (int t = 0; t < 4; ++t) {
      f16x4 bf = *(const f16x4*)&r2[((cb + t) * 16 + r16) * 128 + kk * 16 + g4 * 4];
      acc3[t] = mfma16(af, bf, acc3[t]);
    }
  }
  float* obase = outp + ((size_t)b * Sn + (size_t)c * 64 + mr * 16 + g4 * 4) * Dn;
#pragma unroll
  for (int t = 0; t < 4; ++t)
#pragma unroll
    for (int j = 0; j < 4; ++j)
      obase[(size_t)j * Dn + (cb + t) * 16 + r16] = acc3[t][j];
}

extern "C" void kernel_launch(void* const* d_in, const int* in_sizes, int n_in,
                              void* d_out, int out_size, void* d_ws, size_t ws_size,
                              hipStream_t stream) {
  const float* x = (const float*)d_in[0];
  const float* Wq = (const float*)d_in[1];
  const float* Wk = (const float*)d_in[2];
  const float* Wv = (const float*)d_in[3];
  const float* gw = (const float*)d_in[4];
  const float* gb = (const float*)d_in[5];
  const float* Wout = (const float*)d_in[6];

  char* ws = (char*)d_ws;
  f16* aT = (f16*)(ws + 0);                      // 32 KB
  f16* r2 = (f16*)(ws + 32768);                  // 32 KB
  float* gavg = (float*)(ws + 65536);            // 4 KB
  f16* wtg = (f16*)(ws + 69632);                 // 32 MB (Y row-major)
  f16* mtg = (f16*)(ws + 69632 + 33554432);      // 32 MB (Yhat exclusive prefix)

  k_prep<<<dim3(2), dim3(256), 0, stream>>>(Wq, Wk, Wv, Wout, aT, r2);
  k_phase1<<<dim3(Bn * NCn), dim3(512), 0, stream>>>(x, gw, gb, wtg, gavg);
  k_scan<<<dim3(Bn * 64), dim3(256), 0, stream>>>(wtg, gavg, mtg);
  k_out<<<dim3(Bn * NCn), dim3(512), 0, stream>>>(x, aT, r2, mtg, (float*)d_out);
}

// Round 4
// 63.975 us; speedup vs baseline: 2.5238x; 1.6903x over previous
//
#include <hip/hip_runtime.h>

#define Bn 8
#define Sn 8192
#define Dn 128
#define NCn 128

typedef _Float16 f16;
typedef f16 f16x2 __attribute__((ext_vector_type(2)));
typedef f16 f16x4 __attribute__((ext_vector_type(4)));
typedef float f32x4 __attribute__((ext_vector_type(4)));

static __device__ __forceinline__ f32x4 mfma16(f16x4 a, f16x4 b, f32x4 c) {
  return __builtin_amdgcn_mfma_f32_16x16x16f16(a, b, c, 0, 0, 0);
}

// Validated fragment conventions for mfma_f32_16x16x16f16 (rounds 0,2):
//   A-frag: lane l, reg j = A_op[l&15][4*(l>>4)+j]
//   B-frag: lane l, reg j = B_op[4*(l>>4)+j][l&15]
//   D-frag: lane l, reg j = D[4*(l>>4)+j][l&15]
// Identities used here (derived, this round):
//   D-frag of u == A-frag of u^T        (in-register reuse)
//   D-frag of tile (r,c), packed at [(r*8+c)*64+lane], == B-frag of that
//   matrix for contraction over its rows (packed-frag store/load).

// dst[c*136 + r] = (f16)src[r][c]  (transpose, pitch 136)
static __device__ __forceinline__ void stage_T136(const float* __restrict__ src,
                                                  f16* __restrict__ dst, int tid) {
#pragma unroll
  for (int ii = 0; ii < 4; ++ii) {
    int id = ii * 256 + tid;
    int r4 = id >> 5, c4 = id & 31;
    float4 row[4];
#pragma unroll
    for (int i = 0; i < 4; ++i)
      row[i] = *(const float4*)(src + (r4 * 4 + i) * 128 + c4 * 4);
#pragma unroll
    for (int j = 0; j < 4; ++j) {
      f16x4 col = {(f16)(((const float*)&row[0])[j]), (f16)(((const float*)&row[1])[j]),
                   (f16)(((const float*)&row[2])[j]), (f16)(((const float*)&row[3])[j])};
      *(f16x4*)&dst[(c4 * 4 + j) * 136 + r4 * 4] = col;
    }
  }
}

// ---- precompute: wg0: Amat = Wq^T Wk ; wg1: r2 = Wout Wv = B^T. Both row-major f16. ----
__global__ __launch_bounds__(256) void k_prep(
    const float* __restrict__ Wq, const float* __restrict__ Wk,
    const float* __restrict__ Wv, const float* __restrict__ Wout,
    f16* __restrict__ Amat, f16* __restrict__ r2) {
  __shared__ __align__(16) f16 L[128 * 136];
  __shared__ __align__(16) f16 R[128 * 136];
  const int tid = threadIdx.x;
  if (blockIdx.x == 0) {
    // Amat = Wq^T Wk : A_op = Wq^T -> L = Wq^T ; B_op = Wk -> R = Wk^T
    stage_T136(Wq, L, tid);
    stage_T136(Wk, R, tid);
  } else {
    // r2 = Wout Wv : A_op = Wout (row-major copy) ; B_op = Wv -> R = Wv^T
    int r = tid >> 1, h = tid & 1;
#pragma unroll
    for (int i = 0; i < 16; ++i) {
      float4 v = *(const float4*)(Wout + r * 128 + h * 64 + i * 4);
      f16x4 o = {(f16)v.x, (f16)v.y, (f16)v.z, (f16)v.w};
      *(f16x4*)&L[r * 136 + h * 64 + i * 4] = o;
    }
    stage_T136(Wv, R, tid);
  }
  __syncthreads();
  const int w = tid >> 6, lane = tid & 63, r16 = lane & 15, g4 = lane >> 4;
  f32x4 acc[2][8] = {};
#pragma unroll
  for (int kk = 0; kk < 8; ++kk) {
    f16x4 af0 = *(f16x4*)&L[((2 * w) * 16 + r16) * 136 + kk * 16 + g4 * 4];
    f16x4 af1 = *(f16x4*)&L[((2 * w + 1) * 16 + r16) * 136 + kk * 16 + g4 * 4];
#pragma unroll
    for (int ct = 0; ct < 8; ++ct) {
      f16x4 bf = *(f16x4*)&R[(ct * 16 + r16) * 136 + kk * 16 + g4 * 4];
      acc[0][ct] = mfma16(af0, bf, acc[0][ct]);
      acc[1][ct] = mfma16(af1, bf, acc[1][ct]);
    }
  }
  f16* dst = (blockIdx.x == 0) ? Amat : r2;
#pragma unroll
  for (int rr = 0; rr < 2; ++rr)
#pragma unroll
    for (int ct = 0; ct < 8; ++ct)
#pragma unroll
      for (int j = 0; j < 4; ++j)
        dst[((2 * w + rr) * 16 + g4 * 4 + j) * 128 + ct * 16 + r16] = (f16)acc[rr][ct][j];
}

// ---- fused: gate, u = x A^T, v = x B, Z = (g.u)^T v, packed-frag output ----
__global__ __launch_bounds__(512, 4) void k_phase1(
    const float* __restrict__ x, const float* __restrict__ gw, const float* __restrict__ gb,
    const f16* __restrict__ Amat, const f16* __restrict__ r2,
    f16x4* __restrict__ wtg, float* __restrict__ gavg) {
  __shared__ __align__(16) f16 Xs[64][136];
  __shared__ __align__(16) f16x4 vP[4096];  // packed v D-frags, 32 KB
  __shared__ float gs[64];
  const int blk = blockIdx.x, b = blk >> 7, c = blk & 127;
  const int tid = threadIdx.x;
  {
    int s = tid >> 3, sub = tid & 7;
    const float* xrow = x + ((size_t)b * Sn + (size_t)c * 64 + s) * Dn;
    float gpart = 0.f;
#pragma unroll
    for (int i = 0; i < 4; ++i) {
      int col = sub * 4 + i * 32;
      float4 v = *(const float4*)(xrow + col);
      float4 g = *(const float4*)(gw + col);
      gpart += v.x * g.x + v.y * g.y + v.z * g.z + v.w * g.w;
      f16x4 h = {(f16)v.x, (f16)v.y, (f16)v.z, (f16)v.w};
      *(f16x4*)&Xs[s][col] = h;
    }
    gpart += __shfl_xor(gpart, 1);
    gpart += __shfl_xor(gpart, 2);
    gpart += __shfl_xor(gpart, 4);
    if (sub == 0) gs[s] = 1.f / (1.f + __expf(-(gpart + gb[0])));
  }
  __syncthreads();
  if (tid == 0) {
    float sum = 0.f;
#pragma unroll
    for (int i = 0; i < 64; ++i) sum += gs[i];
    gavg[blk] = sum * (1.f / 64.f);
  }
  const int w = tid >> 6, lane = tid & 63, r16 = lane & 15, g4 = lane >> 4;

  // u,v: wave w owns col-tile ct=w of both; per kk: 2 global B-frags + 4 LDS A-frags -> 8 MFMA
  f32x4 uacc[4] = {}, vacc[4] = {};
#pragma unroll
  for (int kk = 0; kk < 8; ++kk) {
    f16x4 bu = *(const f16x4*)&Amat[(w * 16 + r16) * 128 + kk * 16 + g4 * 4];
    f16x4 bv = *(const f16x4*)&r2[(w * 16 + r16) * 128 + kk * 16 + g4 * 4];
#pragma unroll
    for (int mr = 0; mr < 4; ++mr) {
      f16x4 af = *(f16x4*)&Xs[mr * 16 + r16][kk * 16 + g4 * 4];
      uacc[mr] = mfma16(af, bu, uacc[mr]);
      vacc[mr] = mfma16(af, bv, vacc[mr]);
    }
  }
  // pack v D-frags to LDS; g-scale u D-frags in-register (= A-frags of (g.u)^T)
  f16x4 ua[4];
#pragma unroll
  for (int mr = 0; mr < 4; ++mr) {
    float g0 = gs[mr * 16 + g4 * 4 + 0], g1 = gs[mr * 16 + g4 * 4 + 1];
    float g2 = gs[mr * 16 + g4 * 4 + 2], g3 = gs[mr * 16 + g4 * 4 + 3];
    f16x4 uh = {(f16)(uacc[mr][0] * g0), (f16)(uacc[mr][1] * g1),
                (f16)(uacc[mr][2] * g2), (f16)(uacc[mr][3] * g3)};
    ua[mr] = uh;
    f16x4 vh = {(f16)vacc[mr][0], (f16)vacc[mr][1], (f16)vacc[mr][2], (f16)vacc[mr][3]};
    vP[(mr * 8 + w) * 64 + lane] = vh;
  }
  __syncthreads();

  // Z row-tile w: A-frag[ks] = ua[ks] (in-register), B-frag from vP packed
  f32x4 z[8] = {};
#pragma unroll
  for (int ks = 0; ks < 4; ++ks)
#pragma unroll
    for (int ct = 0; ct < 8; ++ct)
      z[ct] = mfma16(ua[ks], vP[(ks * 8 + ct) * 64 + lane], z[ct]);

  f16x4* wdst = wtg + (size_t)blk * 4096;
#pragma unroll
  for (int ct = 0; ct < 8; ++ct) {
    f16x4 zh = {(f16)z[ct][0], (f16)z[ct][1], (f16)z[ct][2], (f16)z[ct][3]};
    wdst[(w * 8 + ct) * 64 + lane] = zh;
  }
}

// ---- per-element scalar-decay scan, f16x2 vectorized, 16-deep prefetch ----
__global__ __launch_bounds__(256) void k_scan(
    const uint* __restrict__ wtg, const float* __restrict__ gavg, uint* __restrict__ mtg) {
  const int blk = blockIdx.x;  // 256 blocks: b = blk>>5
  const int b = blk >> 5;
  const int e = (blk & 31) * 256 + threadIdx.x;  // uint index 0..8191
  const uint* wp = wtg + (size_t)b * (NCn * 8192) + e;
  uint* mp = mtg + (size_t)b * (NCn * 8192) + e;
  const float* ga = gavg + b * NCn;
  float M0 = 0.f, M1 = 0.f;
  uint ubuf[16];
  float abuf[16];
#pragma unroll
  for (int i = 0; i < 16; ++i) {
    ubuf[i] = wp[(size_t)i * 8192];
    abuf[i] = ga[i];
  }
  for (int g = 0; g < 8; ++g) {
    uint un[16];
    float an[16];
    if (g < 7) {
#pragma unroll
      for (int i = 0; i < 16; ++i) {
        un[i] = wp[(size_t)((g + 1) * 16 + i) * 8192];
        an[i] = ga[(g + 1) * 16 + i];
      }
    }
#pragma unroll
    for (int i = 0; i < 16; ++i) {
      int cc = g * 16 + i;
      f16x2 mv = {(f16)M0, (f16)M1};
      mp[(size_t)cc * 8192] = __builtin_bit_cast(uint, mv);
      f16x2 wv = __builtin_bit_cast(f16x2, ubuf[i]);
      float d = 1.f - abuf[i];
      M0 = d * M0 + (float)wv[0];
      M1 = d * M1 + (float)wv[1];
    }
#pragma unroll
    for (int i = 0; i < 16; ++i) { ubuf[i] = un[i]; abuf[i] = an[i]; }
  }
}

// ---- out_c = x_c Zhat_{c-1} : single GEMM, packed B-frags from LDS ----
__global__ __launch_bounds__(512, 4) void k_out(
    const float* __restrict__ x, const f16x4* __restrict__ mtg, float* __restrict__ outp) {
  __shared__ __align__(16) f16 Xs[64][136];
  __shared__ __align__(16) f16x4 zP[4096];  // 32 KB
  const int blk = blockIdx.x, b = blk >> 7, c = blk & 127;
  const int tid = threadIdx.x;
  {
    int s = tid >> 3, sub = tid & 7;
    const float* xrow = x + ((size_t)b * Sn + (size_t)c * 64 + s) * Dn;
#pragma unroll
    for (int i = 0; i < 4; ++i) {
      int col = sub * 4 + i * 32;
      float4 v = *(const float4*)(xrow + col);
      f16x4 h = {(f16)v.x, (f16)v.y, (f16)v.z, (f16)v.w};
      *(f16x4*)&Xs[s][col] = h;
    }
    const uint4* src = (const uint4*)(mtg + (size_t)blk * 4096);
    uint4* dst = (uint4*)zP;
#pragma unroll
    for (int i = 0; i < 4; ++i) {
      int idx = tid + i * 512;  // 2048 uint4 = 32 KB
      dst[idx] = src[idx];
    }
  }
  __syncthreads();
  const int w = tid >> 6, lane = tid & 63, r16 = lane & 15, g4 = lane >> 4;
  const int mr = w & 3, cb = (w >> 2) * 4;
  f32x4 acc[4] = {};
#pragma unroll
  for (int kk = 0; kk < 8; ++kk) {
    f16x4 af = *(f16x4*)&Xs[mr * 16 + r16][kk * 16 + g4 * 4];
#pragma unroll
    for (int t = 0; t < 4; ++t)
      acc[t] = mfma16(af, zP[(kk * 8 + cb + t) * 64 + lane], acc[t]);
  }
  float* obase = outp + ((size_t)b * Sn + (size_t)c * 64 + mr * 16 + g4 * 4) * Dn;
#pragma unroll
  for (int t = 0; t < 4; ++t)
#pragma unroll
    for (int j = 0; j < 4; ++j)
      obase[(size_t)j * Dn + (cb + t) * 16 + r16] = acc[t][j];
}

extern "C" void kernel_launch(void* const* d_in, const int* in_sizes, int n_in,
                              void* d_out, int out_size, void* d_ws, size_t ws_size,
                              hipStream_t stream) {
  const float* x = (const float*)d_in[0];
  const float* Wq = (const float*)d_in[1];
  const float* Wk = (const float*)d_in[2];
  const float* Wv = (const float*)d_in[3];
  const float* gw = (const float*)d_in[4];
  const float* gb = (const float*)d_in[5];
  const float* Wout = (const float*)d_in[6];

  char* ws = (char*)d_ws;
  f16* Amat = (f16*)(ws + 0);                    // 32 KB
  f16* r2 = (f16*)(ws + 32768);                  // 32 KB
  float* gavg = (float*)(ws + 65536);            // 4 KB
  f16* wtg = (f16*)(ws + 69632);                 // 32 MB (Z, packed frags)
  f16* mtg = (f16*)(ws + 69632 + 33554432);      // 32 MB (Zhat exclusive prefix)

  k_prep<<<dim3(2), dim3(256), 0, stream>>>(Wq, Wk, Wv, Wout, Amat, r2);
  k_phase1<<<dim3(Bn * NCn), dim3(512), 0, stream>>>(x, gw, gb, Amat, r2, (f16x4*)wtg, gavg);
  k_scan<<<dim3(256), dim3(256), 0, stream>>>((const uint*)wtg, gavg, (uint*)mtg);
  k_out<<<dim3(Bn * NCn), dim3(512), 0, stream>>>(x, (const f16x4*)mtg, (float*)d_out);
}